// Round 1
// baseline (300.647 us; speedup 1.0000x reference)
//
#include <hip/hip_runtime.h>
#include <stdint.h>

#define NROW 4096
#define NDIM 128
#define KNEG 4092
#define INF_VAL 1e30f
#define BUCKETS 2048
#define GTOT ((size_t)NROW * (size_t)KNEG)   // 16,760,832 = 1024 * 16368
#define DISTBLKS 1024                         // 32x32 tiles of 128x128
#define DSTR 68

typedef __attribute__((ext_vector_type(8))) short short8;
typedef __attribute__((ext_vector_type(4))) float f32x4;

// ---------------- Threefry-2x32-20, key = (0, 42) ----------------
__device__ __forceinline__ uint32_t rotl32(uint32_t v, int d) {
  return __builtin_rotateleft32(v, (unsigned)d);
}

__device__ __forceinline__ void threefry2x32(uint32_t x0, uint32_t x1,
                                             uint32_t& y0, uint32_t& y1) {
  const uint32_t k0 = 0u, k1 = 42u;
  const uint32_t k2 = 0x1BD11BDAu ^ k0 ^ k1;
  uint32_t v0 = x0 + k0, v1 = x1 + k1;
#define TF_R(r) v0 += v1; v1 = rotl32(v1, r); v1 ^= v0;
  TF_R(13) TF_R(15) TF_R(26) TF_R(6)
  v0 += k1; v1 += k2 + 1u;
  TF_R(17) TF_R(29) TF_R(16) TF_R(24)
  v0 += k2; v1 += k0 + 2u;
  TF_R(13) TF_R(15) TF_R(26) TF_R(6)
  v0 += k0; v1 += k1 + 3u;
  TF_R(17) TF_R(29) TF_R(16) TF_R(24)
  v0 += k1; v1 += k2 + 4u;
  TF_R(13) TF_R(15) TF_R(26) TF_R(6)
  v0 += k2; v1 += k0 + 5u;
#undef TF_R
  y0 = v0; y1 = v1;
}

__device__ __forceinline__ float gumbel_ref(uint32_t f) {
  uint32_t y0, y1;
  threefry2x32(0u, f, y0, y1);
  uint32_t m = y1 >> 9;
  float fm = (float)m;                                     // exact (m < 2^24)
  float nl = fmaf(-0.69314718f, __log2f(fm), 15.942385f);  // ln2*(23-log2 m)
  if (m == 0u) nl = 87.33655f;                             // -log(tiny)
  return -0.69314718f * __log2f(nl);
}

__device__ __forceinline__ float softplus_ref(float x) {
  return fmaxf(x, 0.0f) + log1pf(expf(-fabsf(x)));
}

__device__ __forceinline__ ushort f2h(float f) {
  _Float16 h = (_Float16)f;
  return *(ushort*)&h;
}
__device__ __forceinline__ float h2f(ushort u) {
  _Float16 h = *(_Float16*)&u;
  return (float)h;
}
__device__ __forceinline__ float bf2f(ushort u) {
  return __uint_as_float(((uint32_t)u) << 16);
}
__device__ __forceinline__ ushort f2bf(float f) {
  uint32_t u = __float_as_uint(f);
  u += 0x7fffu + ((u >> 16) & 1u);
  return (ushort)(u >> 16);
}

// bucket = bf16 code (monotone & injective for positive floats); every bucket
// holds only exactly-equal values => scatter ordinal IS the exact rank offset.
__device__ __forceinline__ int bucket_code(ushort code) {
  return min(max((int)code - 0x4000, 0), BUCKETS - 1);
}

// ---------------- kernel A: sumsq + fp32->bf16 convert (4 rows/block) -------
__global__ __launch_bounds__(256) void prep_kernel(const float* __restrict__ X,
                                                   float* __restrict__ sq,
                                                   ushort* __restrict__ Xbf,
                                                   uint32_t* __restrict__ cnt) {
  const int tid = threadIdx.x;
  const int lane = tid & 63;
  const int i = (blockIdx.x << 2) + (tid >> 6);
  float2 v = ((const float2*)(X + (size_t)i * NDIM))[lane];
  float s = v.x * v.x + v.y * v.y;
  for (int o = 32; o > 0; o >>= 1) s += __shfl_down(s, o);
  if (lane == 0) sq[i] = s;
  ushort2 h;
  h.x = f2bf(v.x);
  h.y = f2bf(v.y);
  ((ushort2*)(Xbf + (size_t)i * NDIM))[lane] = h;
  if (blockIdx.x == 0 && tid == 0) *cnt = 0u;  // ticket for fused reduce
}

// ---------------- kernel B: dist tile + gumbel slice per block --------------
__global__ __launch_bounds__(256) void dist_gumbel(const ushort* __restrict__ Xbf,
                                                   const float* __restrict__ sq,
                                                   ushort* __restrict__ distb,
                                                   ushort* __restrict__ gh) {
  __shared__ ushort Als[128 * DSTR];
  __shared__ ushort Bls[128 * DSTR];
  const int tid = threadIdx.x;
  const int bi = blockIdx.x >> 5, bj = blockIdx.x & 31;
  const int wave = tid >> 6, lane = tid & 63;
  const int q = lane >> 4, ln = lane & 15;
  const ushort* Ag = Xbf + (size_t)bi * 128 * NDIM;
  const ushort* Bg = Xbf + (size_t)bj * 128 * NDIM;

  f32x4 acc[8][2];
#pragma unroll
  for (int mt = 0; mt < 8; ++mt)
#pragma unroll
    for (int nt = 0; nt < 2; ++nt) acc[mt][nt] = (f32x4){0.f, 0.f, 0.f, 0.f};

  for (int kh = 0; kh < 2; ++kh) {
    if (kh) __syncthreads();
#pragma unroll
    for (int t = 0; t < 4; ++t) {
      int c = tid + 256 * t;
      int r = c >> 3, k8 = (c & 7) << 3;
      *(short8*)&Als[r * DSTR + k8] =
          *(const short8*)(Ag + (size_t)r * NDIM + kh * 64 + k8);
      *(short8*)&Bls[r * DSTR + k8] =
          *(const short8*)(Bg + (size_t)r * NDIM + kh * 64 + k8);
    }
    __syncthreads();
#pragma unroll
    for (int k0 = 0; k0 < 64; k0 += 32) {
      int kf = k0 + q * 8;
      short8 a[8], b[2];
#pragma unroll
      for (int mt = 0; mt < 8; ++mt)
        a[mt] = *(const short8*)&Als[(mt * 16 + ln) * DSTR + kf];
#pragma unroll
      for (int nt = 0; nt < 2; ++nt)
        b[nt] = *(const short8*)&Bls[(wave * 32 + 2 * ln + nt) * DSTR + kf];
#pragma unroll
      for (int mt = 0; mt < 8; ++mt)
#pragma unroll
        for (int nt = 0; nt < 2; ++nt)
          acc[mt][nt] = __builtin_amdgcn_mfma_f32_16x16x32_bf16(
              a[mt], b[nt], acc[mt][nt], 0, 0, 0);
    }
  }

  const int jcol = bj * 128 + wave * 32 + 2 * ln;
  float sqj0 = sq[jcol], sqj1 = sq[jcol + 1];
#pragma unroll
  for (int mt = 0; mt < 8; ++mt) {
    int ibase = bi * 128 + mt * 16 + q * 4;
#pragma unroll
    for (int r = 0; r < 4; ++r) {
      int i = ibase + r;
      float sqi = sq[i];
      float dx = sqrtf(fmaxf(sqi + sqj0 - 2.0f * acc[mt][0][r], 1e-12f));
      float dy = sqrtf(fmaxf(sqi + sqj1 - 2.0f * acc[mt][1][r], 1e-12f));
      uint32_t pack = ((uint32_t)f2bf(dy) << 16) | (uint32_t)f2bf(dx);
      *(uint32_t*)(distb + (size_t)i * NROW + jcol) = pack;
    }
  }

  if (gh) {
    uint32_t b0 = (uint32_t)blockIdx.x * 16368u;
#pragma unroll
    for (int t = 0; t < 16; ++t) {
      int c = tid + 256 * t;
      if (c < 4092) {
        uint32_t f0 = b0 + (uint32_t)c * 4u;
        ushort4 h;
        h.x = f2h(gumbel_ref(f0 + 0u));
        h.y = f2h(gumbel_ref(f0 + 1u));
        h.z = f2h(gumbel_ref(f0 + 2u));
        h.w = f2h(gumbel_ref(f0 + 3u));
        *(ushort4*)(gh + f0) = h;
      }
    }
  }
}

// ---------------- kernel C: per-row rank + sample + loss + fused reduce -----
// Direct-rank version: no sortc scatter/gather. Each element keeps
// (x, bkt, ord) in registers; rank p = start[bkt] + ord. G row staged in LDS.
// Histogram split across two bank-offset replicas by lane half to halve
// same-address atomic serialization. Bit-identical outputs to prior kernel.
__global__ __launch_bounds__(256) void row_kernel(const ushort* __restrict__ distb,
                                                  const ushort* __restrict__ Gh,
                                                  float4* __restrict__ part,
                                                  uint32_t* __restrict__ cnt,
                                                  float* __restrict__ out) {
  __shared__ alignas(16) int baseA[BUCKETS];            // 8 KB
  __shared__ alignas(16) int baseB_raw[BUCKETS + 16];   // 8 KB + bank offset
  __shared__ alignas(16) ushort Gls[4096];              // 8 KB
  __shared__ float wredf[8];
  __shared__ int wtot[4];
  __shared__ float s_pos[3];
  __shared__ float s_sel[3];
  __shared__ int s_last;
  __shared__ double dsum[4][4];

  int* baseB = baseB_raw + 16;  // bank-shifted by 16 vs baseA

  // aliases — live only after the score pass (barrier-separated)
  float* cscore = (float*)baseA;                     // 768 f
  float* cx     = (float*)baseA + 768;               // 768 f
  int*   crank  = (int*)Gls;                         // 768 i
  float* redf   = (float*)((char*)Gls + 3072);       // 256 f
  int*   redi   = (int*)((char*)Gls + 4096);         // 256 i
  int*   redi2  = (int*)((char*)Gls + 5120);         // 256 i

  const int i = blockIdx.x;
  const int tid = threadIdx.x;
  const int lane = tid & 63, wid = tid >> 6;
  const ushort* row = distb + (size_t)i * NROW;
  const int gbase = i & ~3;

  {
    int4 z4 = (int4){0, 0, 0, 0};
    int4* za = (int4*)baseA;
    za[tid] = z4; za[tid + 256] = z4;
    int4* zb = (int4*)baseB;
    zb[tid] = z4; zb[tid + 256] = z4;
  }

  ushort cd[16];
  float x[16];
  {
    short8 r0 = *(const short8*)(row + tid * 16);
    short8 r1 = *(const short8*)(row + tid * 16 + 8);
#pragma unroll
    for (int k = 0; k < 8; ++k) {
      cd[k] = (ushort)r0[k];     x[k] = bf2f(cd[k]);
      cd[8 + k] = (ushort)r1[k]; x[8 + k] = bf2f(cd[8 + k]);
    }
  }

  // stage Gumbel row into LDS (coalesced dword copies; row is 4B-aligned)
  const uint32_t fbase = (uint32_t)i * (uint32_t)KNEG;
  const ushort* grow = Gh ? (Gh + (size_t)fbase) : nullptr;
  if (grow) {
    const uint32_t* g4 = (const uint32_t*)grow;
    uint32_t* gl = (uint32_t*)Gls;
#pragma unroll
    for (int t = 0; t < 8; ++t) {
      int c = tid + 256 * t;
      if (c < (KNEG / 2)) gl[c] = g4[c];
    }
  }

  if (tid == (gbase >> 4)) {
    float p[3]; int np = 0;
#pragma unroll
    for (int qq = 0; qq < 4; ++qq) {
      int j = gbase + qq;
      if (j != i) p[np++] = x[j & 15];
    }
    float a = p[0], b = p[1], c = p[2], t_;
    if (a > b) { t_ = a; a = b; b = t_; }
    if (b > c) { t_ = b; b = c; c = t_; }
    if (a > b) { t_ = a; a = b; b = t_; }
    s_pos[0] = a; s_pos[1] = b; s_pos[2] = c;
  }

#pragma unroll
  for (int qq = 0; qq < 16; ++qq) {
    int j = tid * 16 + qq;
    if ((j >> 2) == (i >> 2)) { x[qq] = INF_VAL; cd[qq] = 0x7F80u; }
  }
  __syncthreads();

  // ---- histogram (lane-split replicas) + Σx ----
  int pk[16];  // bkt | (ord << 11)
  int* hist = (lane & 32) ? baseB : baseA;
  float ls = 0.f;
#pragma unroll
  for (int qq = 0; qq < 16; ++qq) {
    int b = bucket_code(cd[qq]);
    int o = atomicAdd(&hist[b], 1);
    pk[qq] = b | (o << 11);
    if (x[qq] < 1e29f) ls += x[qq];
  }
  for (int o = 32; o > 0; o >>= 1) ls += __shfl_down(ls, o);
  if (lane == 0) wredf[wid] = ls;
  __syncthreads();
  const float negsum = wredf[0] + wredf[1] + wredf[2] + wredf[3];
  const float mean = negsum / (float)KNEG;

  // ---- per-thread 8-bucket totals via wide LDS loads ----
  int4 a0 = ((const int4*)baseA)[2 * tid];
  int4 a1 = ((const int4*)baseA)[2 * tid + 1];
  int4 b0 = ((const int4*)baseB)[2 * tid];
  int4 b1 = ((const int4*)baseB)[2 * tid + 1];
  int cA[8] = {a0.x, a0.y, a0.z, a0.w, a1.x, a1.y, a1.z, a1.w};
  int tot[8] = {a0.x + b0.x, a0.y + b0.y, a0.z + b0.z, a0.w + b0.w,
                a1.x + b1.x, a1.y + b1.y, a1.z + b1.z, a1.w + b1.w};
  int c8[8]; int lsum = 0;
#pragma unroll
  for (int qq = 0; qq < 8; ++qq) { c8[qq] = lsum; lsum += tot[qq]; }

  float ls2 = 0.f;
#pragma unroll
  for (int qq = 0; qq < 16; ++qq)
    if (x[qq] < 1e29f) { float z = x[qq] - mean; ls2 += z * z; }
  int incl = lsum;
  for (int off = 1; off < 64; off <<= 1) {
    int o = __shfl_up(incl, off);
    if (lane >= off) incl += o;
  }
  for (int o = 32; o > 0; o >>= 1) ls2 += __shfl_down(ls2, o);
  if (lane == 63) wtot[wid] = incl;
  if (lane == 0) wredf[4 + wid] = ls2;
  __syncthreads();
  const float var = (wredf[4] + wredf[5] + wredf[6] + wredf[7]) / (float)KNEG;
  const float stdv = sqrtf(var);
  const float rdenom = __frcp_rn(2.0f * stdv * stdv);
  int excl = incl - lsum;
#pragma unroll
  for (int w = 0; w < 4; ++w) if (w < wid) excl += wtot[w];
  // baseA[b] = global start; baseB[b] = start + cntA (start for B-half lanes)
  ((int4*)baseA)[2 * tid] =
      (int4){excl + c8[0], excl + c8[1], excl + c8[2], excl + c8[3]};
  ((int4*)baseA)[2 * tid + 1] =
      (int4){excl + c8[4], excl + c8[5], excl + c8[6], excl + c8[7]};
  ((int4*)baseB)[2 * tid] =
      (int4){excl + c8[0] + cA[0], excl + c8[1] + cA[1],
             excl + c8[2] + cA[2], excl + c8[3] + cA[3]};
  ((int4*)baseB)[2 * tid + 1] =
      (int4){excl + c8[4] + cA[4], excl + c8[5] + cA[5],
             excl + c8[6] + cA[6], excl + c8[7] + cA[7]};
  __syncthreads();

  // ---- score/top-3 directly from registers: p = start[bkt] + ord ----
  const int* startp = (lane & 32) ? baseB : baseA;
  float t0s = -1e38f, t1s = -1e38f, t2s = -1e38f;
  int   t0r = 0x7fffffff, t1r = 0x7fffffff, t2r = 0x7fffffff;
  float t0x = 0.f, t1x = 0.f, t2x = 0.f;
#pragma unroll
  for (int qq = 0; qq < 16; ++qq) {
    if (x[qq] < 1e29f) {
      int b = pk[qq] & 2047;
      int p = startp[b] + (pk[qq] >> 11);
      float xv = x[qq];
      float z = xv - mean;
      float gv = grow ? h2f(Gls[p]) : gumbel_ref(fbase + (uint32_t)p);
      float sv = fmaf(z * z, rdenom, gv);
      if (sv > t2s || (sv == t2s && p < t2r)) {
        t2s = sv; t2r = p; t2x = xv;
        if (t2s > t1s || (t2s == t1s && t2r < t1r)) {
          float ts = t1s; int tr = t1r; float tx = t1x;
          t1s = t2s; t1r = t2r; t1x = t2x; t2s = ts; t2r = tr; t2x = tx;
        }
        if (t1s > t0s || (t1s == t0s && t1r < t0r)) {
          float ts = t0s; int tr = t0r; float tx = t0x;
          t0s = t1s; t0r = t1r; t0x = t1x; t1s = ts; t1r = tr; t1x = tx;
        }
      }
    }
  }
  __syncthreads();  // baseA/baseB/Gls reads done; aliases become live

  cscore[tid * 3 + 0] = t0s; crank[tid * 3 + 0] = t0r; cx[tid * 3 + 0] = t0x;
  cscore[tid * 3 + 1] = t1s; crank[tid * 3 + 1] = t1r; cx[tid * 3 + 1] = t1x;
  cscore[tid * 3 + 2] = t2s; crank[tid * 3 + 2] = t2r; cx[tid * 3 + 2] = t2x;
  __syncthreads();

  for (int t = 0; t < 3; ++t) {
    float bs = -1e38f; int br = 0x7fffffff; int bidx = 0;
    for (int k = tid; k < 768; k += 256) {
      float s_ = cscore[k]; int r_ = crank[k];
      if (s_ > bs || (s_ == bs && r_ < br)) { bs = s_; br = r_; bidx = k; }
    }
    redf[tid] = bs; redi[tid] = br; redi2[tid] = bidx;
    __syncthreads();
    if (tid < 64) {
      float s0_ = redf[tid]; int r0_ = redi[tid]; int i0_ = redi2[tid];
#pragma unroll
      for (int o = 64; o < 256; o += 64) {
        float s1 = redf[tid + o]; int r1 = redi[tid + o];
        if (s1 > s0_ || (s1 == s0_ && r1 < r0_)) {
          s0_ = s1; r0_ = r1; i0_ = redi2[tid + o];
        }
      }
      for (int off = 32; off > 0; off >>= 1) {
        float s1 = __shfl_down(s0_, off);
        int r1 = __shfl_down(r0_, off);
        int i1 = __shfl_down(i0_, off);
        if (s1 > s0_ || (s1 == s0_ && r1 < r0_)) { s0_ = s1; r0_ = r1; i0_ = i1; }
      }
      if (tid == 0) { s_sel[t] = cx[i0_]; cscore[i0_] = -1e38f; }
    }
    __syncthreads();
  }

  if (tid == 0) {
    float p0 = s_pos[0], p1 = s_pos[1], p2 = s_pos[2];
    float thr = p2 + 0.05f;
    float samp[3]; bool kept[3]; int cntk = 0;
#pragma unroll
    for (int t = 0; t < 3; ++t) {
      samp[t] = s_sel[t];
      kept[t] = samp[t] < thr;
      cntk += kept[t] ? 1 : 0;
    }
    bool any = cntk > 0;
    float pos_loss = 0.5f *
        (softplus_ref(-2.0f * (1.0f - p0)) + softplus_ref(-2.0f * (1.0f - p1)) +
         softplus_ref(-2.0f * (1.0f - p2))) / 3.0f;
    float nsum = 0.0f;
#pragma unroll
    for (int t = 0; t < 3; ++t)
      if (kept[t]) nsum += softplus_ref(20.0f * (1.0f - samp[t]));
    float neg_loss = 0.05f * nsum / (float)(cntk > 0 ? cntk : 1);
    float row_loss = any ? (pos_loss + neg_loss) : 0.0f;
    int first = kept[0] ? 0 : (kept[1] ? 1 : (kept[2] ? 2 : 0));
    float neg0 = samp[first];
    float errv = (any && (p0 < neg0 - 0.1f)) ? 1.0f : 0.0f;

    float* pf = (float*)(part + i);
    __hip_atomic_store(pf + 0, row_loss, __ATOMIC_RELAXED, __HIP_MEMORY_SCOPE_AGENT);
    __hip_atomic_store(pf + 1, errv, __ATOMIC_RELAXED, __HIP_MEMORY_SCOPE_AGENT);
    __hip_atomic_store(pf + 2, p0 + p1 + p2, __ATOMIC_RELAXED, __HIP_MEMORY_SCOPE_AGENT);
    __hip_atomic_store(pf + 3, negsum, __ATOMIC_RELAXED, __HIP_MEMORY_SCOPE_AGENT);
    __threadfence();  // release: partials visible before ticket
    uint32_t tk = __hip_atomic_fetch_add(cnt, 1u, __ATOMIC_ACQ_REL,
                                         __HIP_MEMORY_SCOPE_AGENT);
    s_last = (tk == (uint32_t)(NROW - 1)) ? 1 : 0;
  }
  __syncthreads();

  // ---- last block performs the final reduction (same math as before) ----
  if (s_last) {
    __threadfence();  // acquire
    double s0 = 0.0, s1 = 0.0, s2 = 0.0, s3 = 0.0;
    const float* pf = (const float*)part;
    for (int k = tid; k < NROW; k += 256) {
      float vx = __hip_atomic_load(pf + 4 * k + 0, __ATOMIC_RELAXED, __HIP_MEMORY_SCOPE_AGENT);
      float vy = __hip_atomic_load(pf + 4 * k + 1, __ATOMIC_RELAXED, __HIP_MEMORY_SCOPE_AGENT);
      float vz = __hip_atomic_load(pf + 4 * k + 2, __ATOMIC_RELAXED, __HIP_MEMORY_SCOPE_AGENT);
      float vw = __hip_atomic_load(pf + 4 * k + 3, __ATOMIC_RELAXED, __HIP_MEMORY_SCOPE_AGENT);
      s0 += (double)vx; s1 += (double)vy; s2 += (double)vz; s3 += (double)vw;
    }
    for (int o = 32; o > 0; o >>= 1) {
      s0 += __shfl_down(s0, o); s1 += __shfl_down(s1, o);
      s2 += __shfl_down(s2, o); s3 += __shfl_down(s3, o);
    }
    if (lane == 0) {
      dsum[wid][0] = s0; dsum[wid][1] = s1; dsum[wid][2] = s2; dsum[wid][3] = s3;
    }
    __syncthreads();
    if (tid == 0) {
      double a0 = dsum[0][0] + dsum[1][0] + dsum[2][0] + dsum[3][0];
      double a1 = dsum[0][1] + dsum[1][1] + dsum[2][1] + dsum[3][1];
      double a2 = dsum[0][2] + dsum[1][2] + dsum[2][2] + dsum[3][2];
      double a3 = dsum[0][3] + dsum[1][3] + dsum[2][3] + dsum[3][3];
      out[0] = (float)(a0 / (double)NROW);
      out[1] = (float)(1.0 - a1 / (double)NROW);
      out[2] = (float)(a2 / ((double)NROW * 3.0));
      out[3] = (float)(a3 / ((double)NROW * (double)KNEG));
    }
  }
}

extern "C" void kernel_launch(void* const* d_in, const int* in_sizes, int n_in,
                              void* d_out, int out_size, void* d_ws, size_t ws_size,
                              hipStream_t stream) {
  (void)in_sizes; (void)n_in; (void)out_size;
  const float* X = (const float*)d_in[0];
  float* out = (float*)d_out;
  char* ws = (char*)d_ws;

  ushort* distb = (ushort*)ws;                                     // 32 MiB bf16
  size_t off = (size_t)NROW * NROW * sizeof(ushort);
  float* sq = (float*)(ws + off);            off += NROW * sizeof(float);
  ushort* Xbf = (ushort*)(ws + off);         off += (size_t)NROW * NDIM * sizeof(ushort);
  float4* part = (float4*)(ws + off);        off += (size_t)NROW * sizeof(float4);
  uint32_t* cnt = (uint32_t*)(ws + off);     off += 16;
  // fp16 Gumbel table (32 MB) — only if workspace allows; else inline fallback
  ushort* Gh = nullptr;
  if (ws_size >= off + GTOT * sizeof(ushort)) Gh = (ushort*)(ws + off);

  prep_kernel<<<NROW / 4, 256, 0, stream>>>(X, sq, Xbf, cnt);
  dist_gumbel<<<DISTBLKS, 256, 0, stream>>>(Xbf, sq, distb, Gh);
  row_kernel<<<NROW, 256, 0, stream>>>(distb, Gh, part, cnt, out);
}

// Round 2
// 175.113 us; speedup vs baseline: 1.7169x; 1.7169x over previous
//
#include <hip/hip_runtime.h>
#include <stdint.h>

#define NROW 4096
#define NDIM 128
#define KNEG 4092
#define INF_VAL 1e30f
#define BUCKETS 2048
#define GTOT ((size_t)NROW * (size_t)KNEG)   // 16,760,832 = 1024 * 16368
#define DISTBLKS 1024                         // gumbel grid; 528 do tiles
#define NTILEP 528                            // 32*33/2 upper-triangle tiles
#define DSTR 68
#define TSTR 130                              // transpose LDS row stride (ushort)

typedef __attribute__((ext_vector_type(8))) short short8;
typedef __attribute__((ext_vector_type(4))) float f32x4;

// ---------------- Threefry-2x32-20, key = (0, 42) ----------------
__device__ __forceinline__ uint32_t rotl32(uint32_t v, int d) {
  return __builtin_rotateleft32(v, (unsigned)d);
}

__device__ __forceinline__ void threefry2x32(uint32_t x0, uint32_t x1,
                                             uint32_t& y0, uint32_t& y1) {
  const uint32_t k0 = 0u, k1 = 42u;
  const uint32_t k2 = 0x1BD11BDAu ^ k0 ^ k1;
  uint32_t v0 = x0 + k0, v1 = x1 + k1;
#define TF_R(r) v0 += v1; v1 = rotl32(v1, r); v1 ^= v0;
  TF_R(13) TF_R(15) TF_R(26) TF_R(6)
  v0 += k1; v1 += k2 + 1u;
  TF_R(17) TF_R(29) TF_R(16) TF_R(24)
  v0 += k2; v1 += k0 + 2u;
  TF_R(13) TF_R(15) TF_R(26) TF_R(6)
  v0 += k0; v1 += k1 + 3u;
  TF_R(17) TF_R(29) TF_R(16) TF_R(24)
  v0 += k1; v1 += k2 + 4u;
  TF_R(13) TF_R(15) TF_R(26) TF_R(6)
  v0 += k2; v1 += k0 + 5u;
#undef TF_R
  y0 = v0; y1 = v1;
}

__device__ __forceinline__ float gumbel_ref(uint32_t f) {
  uint32_t y0, y1;
  threefry2x32(0u, f, y0, y1);
  uint32_t m = y1 >> 9;
  float fm = (float)m;                                     // exact (m < 2^24)
  float nl = fmaf(-0.69314718f, __log2f(fm), 15.942385f);  // ln2*(23-log2 m)
  if (m == 0u) nl = 87.33655f;                             // -log(tiny)
  return -0.69314718f * __log2f(nl);
}

__device__ __forceinline__ float softplus_ref(float x) {
  return fmaxf(x, 0.0f) + log1pf(expf(-fabsf(x)));
}

__device__ __forceinline__ ushort f2h(float f) {
  _Float16 h = (_Float16)f;
  return *(ushort*)&h;
}
__device__ __forceinline__ float h2f(ushort u) {
  _Float16 h = *(_Float16*)&u;
  return (float)h;
}
__device__ __forceinline__ float bf2f(ushort u) {
  return __uint_as_float(((uint32_t)u) << 16);
}
__device__ __forceinline__ ushort f2bf(float f) {
  uint32_t u = __float_as_uint(f);
  u += 0x7fffu + ((u >> 16) & 1u);
  return (ushort)(u >> 16);
}

// bucket = bf16 code (monotone & injective for positive floats); every bucket
// holds only exactly-equal values => scatter position IS the exact rank.
__device__ __forceinline__ int bucket_code(ushort code) {
  return min(max((int)code - 0x4000, 0), BUCKETS - 1);
}

// ---------------- kernel A: sumsq + fp32->bf16 convert (4 rows/block) -------
__global__ __launch_bounds__(256) void prep_kernel(const float* __restrict__ X,
                                                   float* __restrict__ sq,
                                                   ushort* __restrict__ Xbf) {
  const int tid = threadIdx.x;
  const int lane = tid & 63;
  const int i = (blockIdx.x << 2) + (tid >> 6);
  float2 v = ((const float2*)(X + (size_t)i * NDIM))[lane];
  float s = v.x * v.x + v.y * v.y;
  for (int o = 32; o > 0; o >>= 1) s += __shfl_down(s, o);
  if (lane == 0) sq[i] = s;
  ushort2 h;
  h.x = f2bf(v.x);
  h.y = f2bf(v.y);
  ((ushort2*)(Xbf + (size_t)i * NDIM))[lane] = h;
}

// ---------------- kernel B: symmetric dist tiles + gumbel slices ------------
// Blocks [0,528): upper-triangle 128x128 tile (bi<=bj); off-diagonal tiles are
// mirrored via an LDS transpose (bit-identical: MFMA k-order and fp32 adds are
// commutative-exact, so d(i,j)==d(j,i) code-for-code). All 1024 blocks emit a
// 16368-entry gumbel slice (same mapping as before => bit-identical table).
__global__ __launch_bounds__(256) void dist_gumbel(const ushort* __restrict__ Xbf,
                                                   const float* __restrict__ sq,
                                                   ushort* __restrict__ distb,
                                                   ushort* __restrict__ gh) {
  __shared__ ushort Als[128 * DSTR];
  __shared__ ushort Bls[128 * DSTR];
  const int tid = threadIdx.x;
  const int wave = tid >> 6, lane = tid & 63;
  const int q = lane >> 4, ln = lane & 15;

  if (blockIdx.x < NTILEP) {
    // unrank upper-triangle pair (bi <= bj)
    int bi = 0, rem = blockIdx.x;
    while (rem >= 32 - bi) { rem -= 32 - bi; ++bi; }
    const int bj = bi + rem;

    const ushort* Ag = Xbf + (size_t)bi * 128 * NDIM;
    const ushort* Bg = Xbf + (size_t)bj * 128 * NDIM;

    f32x4 acc[8][2];
#pragma unroll
    for (int mt = 0; mt < 8; ++mt)
#pragma unroll
      for (int nt = 0; nt < 2; ++nt) acc[mt][nt] = (f32x4){0.f, 0.f, 0.f, 0.f};

    for (int kh = 0; kh < 2; ++kh) {
      if (kh) __syncthreads();
#pragma unroll
      for (int t = 0; t < 4; ++t) {
        int c = tid + 256 * t;
        int r = c >> 3, k8 = (c & 7) << 3;
        *(short8*)&Als[r * DSTR + k8] =
            *(const short8*)(Ag + (size_t)r * NDIM + kh * 64 + k8);
        *(short8*)&Bls[r * DSTR + k8] =
            *(const short8*)(Bg + (size_t)r * NDIM + kh * 64 + k8);
      }
      __syncthreads();
#pragma unroll
      for (int k0 = 0; k0 < 64; k0 += 32) {
        int kf = k0 + q * 8;
        short8 a[8], b[2];
#pragma unroll
        for (int mt = 0; mt < 8; ++mt)
          a[mt] = *(const short8*)&Als[(mt * 16 + ln) * DSTR + kf];
#pragma unroll
        for (int nt = 0; nt < 2; ++nt)
          b[nt] = *(const short8*)&Bls[(wave * 32 + 2 * ln + nt) * DSTR + kf];
#pragma unroll
        for (int mt = 0; mt < 8; ++mt)
#pragma unroll
          for (int nt = 0; nt < 2; ++nt)
            acc[mt][nt] = __builtin_amdgcn_mfma_f32_16x16x32_bf16(
                a[mt], b[nt], acc[mt][nt], 0, 0, 0);
      }
    }

    __syncthreads();  // k-loop LDS reads done; Als/Bls reusable as transpose buf

    const bool mirror = (bi != bj);
    const int jl = wave * 32 + 2 * ln;       // local col (even)
    const int jcol = bj * 128 + jl;
    float sqj0 = sq[jcol], sqj1 = sq[jcol + 1];
    // rows jl, jl+1 live in the same half (jl even, halves split at 64)
    ushort* Tb = (jl < 64) ? Als : Bls;
    const int trow = (jl & 63) * TSTR;
#pragma unroll
    for (int mt = 0; mt < 8; ++mt) {
      int il0 = mt * 16 + q * 4;
      int ibase = bi * 128 + il0;
#pragma unroll
      for (int r = 0; r < 4; ++r) {
        int i = ibase + r;
        float sqi = sq[i];
        float dx = sqrtf(fmaxf(sqi + sqj0 - 2.0f * acc[mt][0][r], 1e-12f));
        float dy = sqrtf(fmaxf(sqi + sqj1 - 2.0f * acc[mt][1][r], 1e-12f));
        ushort cx_ = f2bf(dx), cy_ = f2bf(dy);
        uint32_t pack = ((uint32_t)cy_ << 16) | (uint32_t)cx_;
        *(uint32_t*)(distb + (size_t)i * NROW + jcol) = pack;
        if (mirror) {
          Tb[trow + il0 + r] = cx_;           // T[jl][il]
          Tb[trow + TSTR + il0 + r] = cy_;    // T[jl+1][il]
        }
      }
    }

    if (mirror) {
      __syncthreads();
#pragma unroll
      for (int t = 0; t < 32; ++t) {
        int linear = tid + 256 * t;          // 8192 dwords = 128x128 ushorts
        int jr = linear >> 6;                // local row in mirror tile
        int cp = linear & 63;                // dword column pair
        const ushort* Rb = (jr < 64) ? Als : Bls;
        uint32_t pack = *(const uint32_t*)&Rb[(jr & 63) * TSTR + 2 * cp];
        *(uint32_t*)(distb + (size_t)(bj * 128 + jr) * NROW + bi * 128 + 2 * cp) =
            pack;
      }
    }
  }

  if (gh) {
    uint32_t b0 = (uint32_t)blockIdx.x * 16368u;
#pragma unroll
    for (int t = 0; t < 16; ++t) {
      int c = tid + 256 * t;
      if (c < 4092) {
        uint32_t f0 = b0 + (uint32_t)c * 4u;
        ushort4 h;
        h.x = f2h(gumbel_ref(f0 + 0u));
        h.y = f2h(gumbel_ref(f0 + 1u));
        h.z = f2h(gumbel_ref(f0 + 2u));
        h.w = f2h(gumbel_ref(f0 + 3u));
        *(ushort4*)(gh + f0) = h;
      }
    }
  }
}

// ---------------- kernel C: per-row rank + sample + loss (proven R0) --------
__global__ __launch_bounds__(256) void row_kernel(const ushort* __restrict__ distb,
                                                  const ushort* __restrict__ Gh,
                                                  float4* __restrict__ part) {
  __shared__ alignas(16) ushort sortc[NROW];   // 8 KB (bf16 codes, rank-ordered)
  __shared__ alignas(16) int base[BUCKETS];    // 8 KB (bucket STARTs)
  __shared__ float wredf[8];
  __shared__ int wtot[4];
  __shared__ float s_pos[3];
  __shared__ float s_sel[3];

  // aliases — live only after the score pass (barrier-separated)
  float* cscore = (float*)base;                      // 768
  float* cx     = (float*)base + 768;                // 768
  int*   crank  = (int*)sortc;                       // 768
  float* redf   = (float*)((char*)sortc + 3072);     // 256
  int*   redi   = (int*)((char*)sortc + 4096);       // 256
  int*   redi2  = (int*)((char*)sortc + 5120);       // 256

  const int i = blockIdx.x;
  const int tid = threadIdx.x;
  const int lane = tid & 63, wid = tid >> 6;
  const ushort* row = distb + (size_t)i * NROW;
  const int gbase = i & ~3;

  {
    int4* b4 = (int4*)base;
    b4[tid] = (int4){0, 0, 0, 0};
    b4[tid + 256] = (int4){0, 0, 0, 0};
  }

  ushort cd[16];
  float x[16];
  {
    short8 r0 = *(const short8*)(row + tid * 16);
    short8 r1 = *(const short8*)(row + tid * 16 + 8);
#pragma unroll
    for (int k = 0; k < 8; ++k) {
      cd[k] = (ushort)r0[k];     x[k] = bf2f(cd[k]);
      cd[8 + k] = (ushort)r1[k]; x[8 + k] = bf2f(cd[8 + k]);
    }
  }

  if (tid == (gbase >> 4)) {
    float p[3]; int np = 0;
#pragma unroll
    for (int qq = 0; qq < 4; ++qq) {
      int j = gbase + qq;
      if (j != i) p[np++] = x[j & 15];
    }
    float a = p[0], b = p[1], c = p[2], t_;
    if (a > b) { t_ = a; a = b; b = t_; }
    if (b > c) { t_ = b; b = c; c = t_; }
    if (a > b) { t_ = a; a = b; b = t_; }
    s_pos[0] = a; s_pos[1] = b; s_pos[2] = c;
  }

#pragma unroll
  for (int qq = 0; qq < 16; ++qq) {
    int j = tid * 16 + qq;
    if ((j >> 2) == (i >> 2)) { x[qq] = INF_VAL; cd[qq] = 0x7F80u; }
  }
  __syncthreads();

  int bkt[16];
  int ord[16];
  float ls = 0.f;
#pragma unroll
  for (int qq = 0; qq < 16; ++qq) {
    bkt[qq] = bucket_code(cd[qq]);
    ord[qq] = atomicAdd(&base[bkt[qq]], 1);
    if (x[qq] < 1e29f) ls += x[qq];
  }
  for (int o = 32; o > 0; o >>= 1) ls += __shfl_down(ls, o);
  if (lane == 0) wredf[wid] = ls;
  __syncthreads();
  const float negsum = wredf[0] + wredf[1] + wredf[2] + wredf[3];
  const float mean = negsum / (float)KNEG;

  int c8[8]; int lsum = 0;
#pragma unroll
  for (int qq = 0; qq < 8; ++qq) {
    int t_ = base[tid * 8 + qq];
    c8[qq] = lsum; lsum += t_;
  }
  float ls2 = 0.f;
#pragma unroll
  for (int qq = 0; qq < 16; ++qq)
    if (x[qq] < 1e29f) { float z = x[qq] - mean; ls2 += z * z; }
  int incl = lsum;
  for (int off = 1; off < 64; off <<= 1) {
    int o = __shfl_up(incl, off);
    if (lane >= off) incl += o;
  }
  for (int o = 32; o > 0; o >>= 1) ls2 += __shfl_down(ls2, o);
  if (lane == 63) wtot[wid] = incl;
  if (lane == 0) wredf[4 + wid] = ls2;
  __syncthreads();
  const float var = (wredf[4] + wredf[5] + wredf[6] + wredf[7]) / (float)KNEG;
  const float stdv = sqrtf(var);
  const float rdenom = __frcp_rn(2.0f * stdv * stdv);
  int excl = incl - lsum;
#pragma unroll
  for (int w = 0; w < 4; ++w) if (w < wid) excl += wtot[w];
#pragma unroll
  for (int qq = 0; qq < 8; ++qq) base[tid * 8 + qq] = excl + c8[qq];
  __syncthreads();

  // ---- place CODES: pos = start + ordinal (EXACT rank) ----
#pragma unroll
  for (int qq = 0; qq < 16; ++qq) {
    int p = base[bkt[qq]] + ord[qq];
    sortc[p] = cd[qq];
  }
  __syncthreads();

  // ---- prefetch G (16 independent coalesced loads, rank = p) ----
  const uint32_t fbase = (uint32_t)i * (uint32_t)KNEG;
  const ushort* grow = Gh ? (Gh + fbase) : nullptr;
  ushort gcode[16];
  if (grow) {
#pragma unroll
    for (int qq = 0; qq < 16; ++qq) gcode[qq] = grow[tid + 256 * qq];
  }

  // ---- score/top-3: rank = p, loop-free ----
  float t0s = -1e38f, t1s = -1e38f, t2s = -1e38f;
  int   t0r = 0x7fffffff, t1r = 0x7fffffff, t2r = 0x7fffffff;
  float t0x = 0.f, t1x = 0.f, t2x = 0.f;
#pragma unroll
  for (int qq = 0; qq < 16; ++qq) {
    int p = tid + 256 * qq;
    float xv = bf2f(sortc[p]);
    if (p < KNEG) {
      float z = xv - mean;
      float gv = grow ? h2f(gcode[qq]) : gumbel_ref(fbase + (uint32_t)p);
      float sv = fmaf(z * z, rdenom, gv);
      if (sv > t2s || (sv == t2s && p < t2r)) {
        t2s = sv; t2r = p; t2x = xv;
        if (t2s > t1s || (t2s == t1s && t2r < t1r)) {
          float ts = t1s; int tr = t1r; float tx = t1x;
          t1s = t2s; t1r = t2r; t1x = t2x; t2s = ts; t2r = tr; t2x = tx;
        }
        if (t1s > t0s || (t1s == t0s && t1r < t0r)) {
          float ts = t0s; int tr = t0r; float tx = t0x;
          t0s = t1s; t0r = t1r; t0x = t1x; t1s = ts; t1r = tr; t1x = tx;
        }
      }
    }
  }
  __syncthreads();  // sortc/base reads done; aliases become live

  cscore[tid * 3 + 0] = t0s; crank[tid * 3 + 0] = t0r; cx[tid * 3 + 0] = t0x;
  cscore[tid * 3 + 1] = t1s; crank[tid * 3 + 1] = t1r; cx[tid * 3 + 1] = t1x;
  cscore[tid * 3 + 2] = t2s; crank[tid * 3 + 2] = t2r; cx[tid * 3 + 2] = t2x;
  __syncthreads();

  for (int t = 0; t < 3; ++t) {
    float bs = -1e38f; int br = 0x7fffffff; int bidx = 0;
    for (int k = tid; k < 768; k += 256) {
      float s_ = cscore[k]; int r_ = crank[k];
      if (s_ > bs || (s_ == bs && r_ < br)) { bs = s_; br = r_; bidx = k; }
    }
    redf[tid] = bs; redi[tid] = br; redi2[tid] = bidx;
    __syncthreads();
    if (tid < 64) {
      float s0_ = redf[tid]; int r0_ = redi[tid]; int i0_ = redi2[tid];
#pragma unroll
      for (int o = 64; o < 256; o += 64) {
        float s1 = redf[tid + o]; int r1 = redi[tid + o];
        if (s1 > s0_ || (s1 == s0_ && r1 < r0_)) {
          s0_ = s1; r0_ = r1; i0_ = redi2[tid + o];
        }
      }
      for (int off = 32; off > 0; off >>= 1) {
        float s1 = __shfl_down(s0_, off);
        int r1 = __shfl_down(r0_, off);
        int i1 = __shfl_down(i0_, off);
        if (s1 > s0_ || (s1 == s0_ && r1 < r0_)) { s0_ = s1; r0_ = r1; i0_ = i1; }
      }
      if (tid == 0) { s_sel[t] = cx[i0_]; cscore[i0_] = -1e38f; }
    }
    __syncthreads();
  }

  if (tid == 0) {
    float p0 = s_pos[0], p1 = s_pos[1], p2 = s_pos[2];
    float thr = p2 + 0.05f;
    float samp[3]; bool kept[3]; int cnt = 0;
#pragma unroll
    for (int t = 0; t < 3; ++t) {
      samp[t] = s_sel[t];
      kept[t] = samp[t] < thr;
      cnt += kept[t] ? 1 : 0;
    }
    bool any = cnt > 0;
    float pos_loss = 0.5f *
        (softplus_ref(-2.0f * (1.0f - p0)) + softplus_ref(-2.0f * (1.0f - p1)) +
         softplus_ref(-2.0f * (1.0f - p2))) / 3.0f;
    float nsum = 0.0f;
#pragma unroll
    for (int t = 0; t < 3; ++t)
      if (kept[t]) nsum += softplus_ref(20.0f * (1.0f - samp[t]));
    float neg_loss = 0.05f * nsum / (float)(cnt > 0 ? cnt : 1);
    float row_loss = any ? (pos_loss + neg_loss) : 0.0f;
    int first = kept[0] ? 0 : (kept[1] ? 1 : (kept[2] ? 2 : 0));
    float neg0 = samp[first];
    float errv = (any && (p0 < neg0 - 0.1f)) ? 1.0f : 0.0f;
    float4 pr;
    pr.x = row_loss; pr.y = errv; pr.z = p0 + p1 + p2; pr.w = negsum;
    part[i] = pr;
  }
}

// ---------------- reduce: 4096 float4 partials -> 4 outputs ----------------
__global__ __launch_bounds__(256) void reduce_kernel(const float4* __restrict__ part,
                                                     float* __restrict__ out) {
  __shared__ double wsum[4][4];
  const int tid = threadIdx.x;
  const int lane = tid & 63, wid = tid >> 6;
  double s0 = 0.0, s1 = 0.0, s2 = 0.0, s3 = 0.0;
  for (int k = tid; k < NROW; k += 256) {
    float4 v = part[k];
    s0 += (double)v.x; s1 += (double)v.y; s2 += (double)v.z; s3 += (double)v.w;
  }
  for (int o = 32; o > 0; o >>= 1) {
    s0 += __shfl_down(s0, o); s1 += __shfl_down(s1, o);
    s2 += __shfl_down(s2, o); s3 += __shfl_down(s3, o);
  }
  if (lane == 0) {
    wsum[wid][0] = s0; wsum[wid][1] = s1; wsum[wid][2] = s2; wsum[wid][3] = s3;
  }
  __syncthreads();
  if (tid == 0) {
    double a0 = wsum[0][0] + wsum[1][0] + wsum[2][0] + wsum[3][0];
    double a1 = wsum[0][1] + wsum[1][1] + wsum[2][1] + wsum[3][1];
    double a2 = wsum[0][2] + wsum[1][2] + wsum[2][2] + wsum[3][2];
    double a3 = wsum[0][3] + wsum[1][3] + wsum[2][3] + wsum[3][3];
    out[0] = (float)(a0 / (double)NROW);
    out[1] = (float)(1.0 - a1 / (double)NROW);
    out[2] = (float)(a2 / ((double)NROW * 3.0));
    out[3] = (float)(a3 / ((double)NROW * (double)KNEG));
  }
}

extern "C" void kernel_launch(void* const* d_in, const int* in_sizes, int n_in,
                              void* d_out, int out_size, void* d_ws, size_t ws_size,
                              hipStream_t stream) {
  (void)in_sizes; (void)n_in; (void)out_size;
  const float* X = (const float*)d_in[0];
  float* out = (float*)d_out;
  char* ws = (char*)d_ws;

  ushort* distb = (ushort*)ws;                                     // 32 MiB bf16
  size_t off = (size_t)NROW * NROW * sizeof(ushort);
  float* sq = (float*)(ws + off);            off += NROW * sizeof(float);
  ushort* Xbf = (ushort*)(ws + off);         off += (size_t)NROW * NDIM * sizeof(ushort);
  float4* part = (float4*)(ws + off);        off += (size_t)NROW * sizeof(float4);
  // fp16 Gumbel table (32 MB) — only if workspace allows; else inline fallback
  ushort* Gh = nullptr;
  if (ws_size >= off + GTOT * sizeof(ushort)) Gh = (ushort*)(ws + off);

  prep_kernel<<<NROW / 4, 256, 0, stream>>>(X, sq, Xbf);
  dist_gumbel<<<DISTBLKS, 256, 0, stream>>>(Xbf, sq, distb, Gh);
  row_kernel<<<NROW, 256, 0, stream>>>(distb, Gh, part);
  reduce_kernel<<<1, 256, 0, stream>>>(part, out);
}

// Round 3
// 155.151 us; speedup vs baseline: 1.9378x; 1.1287x over previous
//
#include <hip/hip_runtime.h>
#include <stdint.h>

#define NROW 4096
#define NDIM 128
#define KNEG 4092
#define INF_VAL 1e30f
#define BUCKETS 2048
#define GTOT ((size_t)NROW * (size_t)KNEG)   // 16,760,832 = 1024 * 16368
#define DISTBLKS 1024                         // 32x32 tiles of 128x128
#define DSTR 68

typedef __attribute__((ext_vector_type(8))) short short8;
typedef __attribute__((ext_vector_type(4))) float f32x4;

// ---------------- Threefry-2x32-20, key = (0, 42) ----------------
__device__ __forceinline__ uint32_t rotl32(uint32_t v, int d) {
  return __builtin_rotateleft32(v, (unsigned)d);
}

__device__ __forceinline__ void threefry2x32(uint32_t x0, uint32_t x1,
                                             uint32_t& y0, uint32_t& y1) {
  const uint32_t k0 = 0u, k1 = 42u;
  const uint32_t k2 = 0x1BD11BDAu ^ k0 ^ k1;
  uint32_t v0 = x0 + k0, v1 = x1 + k1;
#define TF_R(r) v0 += v1; v1 = rotl32(v1, r); v1 ^= v0;
  TF_R(13) TF_R(15) TF_R(26) TF_R(6)
  v0 += k1; v1 += k2 + 1u;
  TF_R(17) TF_R(29) TF_R(16) TF_R(24)
  v0 += k2; v1 += k0 + 2u;
  TF_R(13) TF_R(15) TF_R(26) TF_R(6)
  v0 += k0; v1 += k1 + 3u;
  TF_R(17) TF_R(29) TF_R(16) TF_R(24)
  v0 += k1; v1 += k2 + 4u;
  TF_R(13) TF_R(15) TF_R(26) TF_R(6)
  v0 += k2; v1 += k0 + 5u;
#undef TF_R
  y0 = v0; y1 = v1;
}

__device__ __forceinline__ float gumbel_ref(uint32_t f) {
  uint32_t y0, y1;
  threefry2x32(0u, f, y0, y1);
  uint32_t m = y1 >> 9;
  float fm = (float)m;                                     // exact (m < 2^24)
  float nl = fmaf(-0.69314718f, __log2f(fm), 15.942385f);  // ln2*(23-log2 m)
  if (m == 0u) nl = 87.33655f;                             // -log(tiny)
  return -0.69314718f * __log2f(nl);
}

__device__ __forceinline__ float softplus_ref(float x) {
  return fmaxf(x, 0.0f) + log1pf(expf(-fabsf(x)));
}

__device__ __forceinline__ ushort f2h(float f) {
  _Float16 h = (_Float16)f;
  return *(ushort*)&h;
}
__device__ __forceinline__ float h2f(ushort u) {
  _Float16 h = *(_Float16*)&u;
  return (float)h;
}
__device__ __forceinline__ float bf2f(ushort u) {
  return __uint_as_float(((uint32_t)u) << 16);
}
__device__ __forceinline__ ushort f2bf(float f) {
  uint32_t u = __float_as_uint(f);
  u += 0x7fffu + ((u >> 16) & 1u);
  return (ushort)(u >> 16);
}

// bucket = bf16 code (monotone & injective for positive floats); every bucket
// holds only exactly-equal values => scatter position IS the exact rank.
__device__ __forceinline__ int bucket_code(ushort code) {
  return min(max((int)code - 0x4000, 0), BUCKETS - 1);
}

// monotone u32 key for f32 (total order, matches > on non-NaN floats)
__device__ __forceinline__ uint32_t fkey(float f) {
  uint32_t b = __float_as_uint(f);
  return b ^ ((uint32_t)((int32_t)b >> 31) | 0x80000000u);
}

// branchless insert into sorted-descending u64 triple
__device__ __forceinline__ void ins3(uint64_t v, uint64_t& t0, uint64_t& t1,
                                     uint64_t& t2) {
  bool c0 = v > t0, c1 = v > t1, c2 = v > t2;
  t2 = c1 ? t1 : (c2 ? v : t2);
  t1 = c0 ? t0 : (c1 ? v : t1);
  t0 = c0 ? v : t0;
}

// merge two sorted-descending triples -> top-3 in (a0,a1,a2)
__device__ __forceinline__ void merge3(uint64_t& a0, uint64_t& a1, uint64_t& a2,
                                       uint64_t b0, uint64_t b1, uint64_t b2) {
  bool sw = b0 > a0;
  uint64_t n0 = sw ? b0 : a0, m0 = sw ? a0 : b0;
  uint64_t n1 = sw ? b1 : a1, m1 = sw ? a1 : b1;
  uint64_t n2 = sw ? b2 : a2;
  a0 = n0;
  bool c = n1 >= m0;  // distinct keys, >= == >
  a1 = c ? n1 : m0;
  uint64_t u = c ? n2 : n1;
  uint64_t w = c ? m0 : m1;
  a2 = (u > w) ? u : w;
}

// ---------------- kernel A: sumsq + fp32->bf16 convert (4 rows/block) -------
__global__ __launch_bounds__(256) void prep_kernel(const float* __restrict__ X,
                                                   float* __restrict__ sq,
                                                   ushort* __restrict__ Xbf) {
  const int tid = threadIdx.x;
  const int lane = tid & 63;
  const int i = (blockIdx.x << 2) + (tid >> 6);
  float2 v = ((const float2*)(X + (size_t)i * NDIM))[lane];
  float s = v.x * v.x + v.y * v.y;
  for (int o = 32; o > 0; o >>= 1) s += __shfl_down(s, o);
  if (lane == 0) sq[i] = s;
  ushort2 h;
  h.x = f2bf(v.x);
  h.y = f2bf(v.y);
  ((ushort2*)(Xbf + (size_t)i * NDIM))[lane] = h;
}

// ---------------- kernel B: dist tile + gumbel slice per block (R0) ---------
__global__ __launch_bounds__(256) void dist_gumbel(const ushort* __restrict__ Xbf,
                                                   const float* __restrict__ sq,
                                                   ushort* __restrict__ distb,
                                                   ushort* __restrict__ gh) {
  __shared__ ushort Als[128 * DSTR];
  __shared__ ushort Bls[128 * DSTR];
  const int tid = threadIdx.x;
  const int bi = blockIdx.x >> 5, bj = blockIdx.x & 31;
  const int wave = tid >> 6, lane = tid & 63;
  const int q = lane >> 4, ln = lane & 15;
  const ushort* Ag = Xbf + (size_t)bi * 128 * NDIM;
  const ushort* Bg = Xbf + (size_t)bj * 128 * NDIM;

  f32x4 acc[8][2];
#pragma unroll
  for (int mt = 0; mt < 8; ++mt)
#pragma unroll
    for (int nt = 0; nt < 2; ++nt) acc[mt][nt] = (f32x4){0.f, 0.f, 0.f, 0.f};

  for (int kh = 0; kh < 2; ++kh) {
    if (kh) __syncthreads();
#pragma unroll
    for (int t = 0; t < 4; ++t) {
      int c = tid + 256 * t;
      int r = c >> 3, k8 = (c & 7) << 3;
      *(short8*)&Als[r * DSTR + k8] =
          *(const short8*)(Ag + (size_t)r * NDIM + kh * 64 + k8);
      *(short8*)&Bls[r * DSTR + k8] =
          *(const short8*)(Bg + (size_t)r * NDIM + kh * 64 + k8);
    }
    __syncthreads();
#pragma unroll
    for (int k0 = 0; k0 < 64; k0 += 32) {
      int kf = k0 + q * 8;
      short8 a[8], b[2];
#pragma unroll
      for (int mt = 0; mt < 8; ++mt)
        a[mt] = *(const short8*)&Als[(mt * 16 + ln) * DSTR + kf];
      // lane owns ADJACENT cols 2*ln, 2*ln+1 -> packed bf16x2 dword stores
#pragma unroll
      for (int nt = 0; nt < 2; ++nt)
        b[nt] = *(const short8*)&Bls[(wave * 32 + 2 * ln + nt) * DSTR + kf];
#pragma unroll
      for (int mt = 0; mt < 8; ++mt)
#pragma unroll
        for (int nt = 0; nt < 2; ++nt)
          acc[mt][nt] = __builtin_amdgcn_mfma_f32_16x16x32_bf16(
              a[mt], b[nt], acc[mt][nt], 0, 0, 0);
    }
  }

  const int jcol = bj * 128 + wave * 32 + 2 * ln;
  float sqj0 = sq[jcol], sqj1 = sq[jcol + 1];
#pragma unroll
  for (int mt = 0; mt < 8; ++mt) {
    int ibase = bi * 128 + mt * 16 + q * 4;
#pragma unroll
    for (int r = 0; r < 4; ++r) {
      int i = ibase + r;
      float sqi = sq[i];
      float dx = sqrtf(fmaxf(sqi + sqj0 - 2.0f * acc[mt][0][r], 1e-12f));
      float dy = sqrtf(fmaxf(sqi + sqj1 - 2.0f * acc[mt][1][r], 1e-12f));
      uint32_t pack = ((uint32_t)f2bf(dy) << 16) | (uint32_t)f2bf(dx);
      *(uint32_t*)(distb + (size_t)i * NROW + jcol) = pack;
    }
  }

  if (gh) {
    uint32_t b0 = (uint32_t)blockIdx.x * 16368u;
#pragma unroll
    for (int t = 0; t < 16; ++t) {
      int c = tid + 256 * t;
      if (c < 4092) {
        uint32_t f0 = b0 + (uint32_t)c * 4u;
        ushort4 h;
        h.x = f2h(gumbel_ref(f0 + 0u));
        h.y = f2h(gumbel_ref(f0 + 1u));
        h.z = f2h(gumbel_ref(f0 + 2u));
        h.w = f2h(gumbel_ref(f0 + 3u));
        *(ushort4*)(gh + f0) = h;
      }
    }
  }
}

// ---------------- kernel C: per-row rank + sample + loss --------------------
// Selection rewritten as packed-u64 keys: (monotone(score) << 32) | (8192 - p).
// Ranks p are unique -> total order; one u64 compare == the old
// (s > || (s== && p<)) predicate. Single-pass block top-3 via one wave.
__global__ __launch_bounds__(256) void row_kernel(const ushort* __restrict__ distb,
                                                  const ushort* __restrict__ Gh,
                                                  float4* __restrict__ part) {
  __shared__ alignas(16) ushort sortc[NROW];   // 8 KB (bf16 codes, rank-ordered)
  __shared__ alignas(16) int base[BUCKETS];    // 8 KB (bucket STARTs)
  __shared__ float wredf[8];
  __shared__ int wtot[4];
  __shared__ float s_pos[3];
  __shared__ int s_selp[3];

  // alias — live only after the score pass (base is dead after scatter)
  uint64_t* cand = (uint64_t*)base;            // 768 * 8B = 6 KB

  const int i = blockIdx.x;
  const int tid = threadIdx.x;
  const int lane = tid & 63, wid = tid >> 6;
  const ushort* row = distb + (size_t)i * NROW;
  const int gbase = i & ~3;

  {
    int4* b4 = (int4*)base;
    b4[tid] = (int4){0, 0, 0, 0};
    b4[tid + 256] = (int4){0, 0, 0, 0};
  }

  ushort cd[16];
  float x[16];
  {
    short8 r0 = *(const short8*)(row + tid * 16);
    short8 r1 = *(const short8*)(row + tid * 16 + 8);
#pragma unroll
    for (int k = 0; k < 8; ++k) {
      cd[k] = (ushort)r0[k];     x[k] = bf2f(cd[k]);
      cd[8 + k] = (ushort)r1[k]; x[8 + k] = bf2f(cd[8 + k]);
    }
  }

  if (tid == (gbase >> 4)) {
    float p[3]; int np = 0;
#pragma unroll
    for (int qq = 0; qq < 4; ++qq) {
      int j = gbase + qq;
      if (j != i) p[np++] = x[j & 15];
    }
    float a = p[0], b = p[1], c = p[2], t_;
    if (a > b) { t_ = a; a = b; b = t_; }
    if (b > c) { t_ = b; b = c; c = t_; }
    if (a > b) { t_ = a; a = b; b = t_; }
    s_pos[0] = a; s_pos[1] = b; s_pos[2] = c;
  }

#pragma unroll
  for (int qq = 0; qq < 16; ++qq) {
    int j = tid * 16 + qq;
    if ((j >> 2) == (i >> 2)) { x[qq] = INF_VAL; cd[qq] = 0x7F80u; }
  }
  __syncthreads();

  int bkt[16];
  int ord[16];
  float ls = 0.f;
#pragma unroll
  for (int qq = 0; qq < 16; ++qq) {
    bkt[qq] = bucket_code(cd[qq]);
    ord[qq] = atomicAdd(&base[bkt[qq]], 1);
    if (x[qq] < 1e29f) ls += x[qq];
  }
  for (int o = 32; o > 0; o >>= 1) ls += __shfl_down(ls, o);
  if (lane == 0) wredf[wid] = ls;
  __syncthreads();
  const float negsum = wredf[0] + wredf[1] + wredf[2] + wredf[3];
  const float mean = negsum / (float)KNEG;

  int c8[8]; int lsum = 0;
#pragma unroll
  for (int qq = 0; qq < 8; ++qq) {
    int t_ = base[tid * 8 + qq];
    c8[qq] = lsum; lsum += t_;
  }
  float ls2 = 0.f;
#pragma unroll
  for (int qq = 0; qq < 16; ++qq)
    if (x[qq] < 1e29f) { float z = x[qq] - mean; ls2 += z * z; }
  int incl = lsum;
  for (int off = 1; off < 64; off <<= 1) {
    int o = __shfl_up(incl, off);
    if (lane >= off) incl += o;
  }
  for (int o = 32; o > 0; o >>= 1) ls2 += __shfl_down(ls2, o);
  if (lane == 63) wtot[wid] = incl;
  if (lane == 0) wredf[4 + wid] = ls2;
  __syncthreads();
  const float var = (wredf[4] + wredf[5] + wredf[6] + wredf[7]) / (float)KNEG;
  const float stdv = sqrtf(var);
  const float rdenom = __frcp_rn(2.0f * stdv * stdv);
  int excl = incl - lsum;
#pragma unroll
  for (int w = 0; w < 4; ++w) if (w < wid) excl += wtot[w];
#pragma unroll
  for (int qq = 0; qq < 8; ++qq) base[tid * 8 + qq] = excl + c8[qq];
  __syncthreads();

  // ---- place CODES: pos = start + ordinal (EXACT rank) ----
#pragma unroll
  for (int qq = 0; qq < 16; ++qq) {
    int p = base[bkt[qq]] + ord[qq];
    sortc[p] = cd[qq];
  }
  __syncthreads();  // last read of base (scatter) done; cand alias free

  // ---- prefetch G (16 independent coalesced loads, rank = p) ----
  const uint32_t fbase = (uint32_t)i * (uint32_t)KNEG;
  const ushort* grow = Gh ? (Gh + fbase) : nullptr;
  ushort gcode[16];
  if (grow) {
#pragma unroll
    for (int qq = 0; qq < 16; ++qq) gcode[qq] = grow[tid + 256 * qq];
  }

  // ---- score/top-3: packed u64, branchless insert ----
  uint64_t t0 = 0, t1 = 0, t2 = 0;  // 0 < key of any real float
#pragma unroll
  for (int qq = 0; qq < 16; ++qq) {
    int p = tid + 256 * qq;
    float xv = bf2f(sortc[p]);
    if (p < KNEG) {
      float z = xv - mean;
      float gv = grow ? h2f(gcode[qq]) : gumbel_ref(fbase + (uint32_t)p);
      float sv = fmaf(z * z, rdenom, gv);
      uint64_t v = ((uint64_t)fkey(sv) << 32) | (uint32_t)(8192 - p);
      ins3(v, t0, t1, t2);
    }
  }
  // sortc stays intact (read again at the end); cand only aliases base
  cand[tid * 3 + 0] = t0;
  cand[tid * 3 + 1] = t1;
  cand[tid * 3 + 2] = t2;
  __syncthreads();

  // ---- single-pass block top-3: wave 0 scans 768 + shfl_xor triple-merge ---
  if (wid == 0) {
    uint64_t a0 = 0, a1 = 0, a2 = 0;
#pragma unroll
    for (int k = 0; k < 12; ++k) {
      uint64_t v = cand[lane + 64 * k];
      ins3(v, a0, a1, a2);
    }
#pragma unroll
    for (int m = 32; m > 0; m >>= 1) {
      uint64_t b0 = __shfl_xor((unsigned long long)a0, m);
      uint64_t b1 = __shfl_xor((unsigned long long)a1, m);
      uint64_t b2 = __shfl_xor((unsigned long long)a2, m);
      merge3(a0, a1, a2, b0, b1, b2);
    }
    if (lane == 0) {
      s_selp[0] = 8192 - (int)(uint32_t)a0;
      s_selp[1] = 8192 - (int)(uint32_t)a1;
      s_selp[2] = 8192 - (int)(uint32_t)a2;
    }
  }
  __syncthreads();

  if (tid == 0) {
    float p0 = s_pos[0], p1 = s_pos[1], p2 = s_pos[2];
    float thr = p2 + 0.05f;
    float samp[3]; bool kept[3]; int cnt = 0;
#pragma unroll
    for (int t = 0; t < 3; ++t) {
      samp[t] = bf2f(sortc[s_selp[t]]);
      kept[t] = samp[t] < thr;
      cnt += kept[t] ? 1 : 0;
    }
    bool any = cnt > 0;
    float pos_loss = 0.5f *
        (softplus_ref(-2.0f * (1.0f - p0)) + softplus_ref(-2.0f * (1.0f - p1)) +
         softplus_ref(-2.0f * (1.0f - p2))) / 3.0f;
    float nsum = 0.0f;
#pragma unroll
    for (int t = 0; t < 3; ++t)
      if (kept[t]) nsum += softplus_ref(20.0f * (1.0f - samp[t]));
    float neg_loss = 0.05f * nsum / (float)(cnt > 0 ? cnt : 1);
    float row_loss = any ? (pos_loss + neg_loss) : 0.0f;
    int first = kept[0] ? 0 : (kept[1] ? 1 : (kept[2] ? 2 : 0));
    float neg0 = samp[first];
    float errv = (any && (p0 < neg0 - 0.1f)) ? 1.0f : 0.0f;
    float4 pr;
    pr.x = row_loss; pr.y = errv; pr.z = p0 + p1 + p2; pr.w = negsum;
    part[i] = pr;
  }
}

// ---------------- reduce: 4096 float4 partials -> 4 outputs ----------------
__global__ __launch_bounds__(256) void reduce_kernel(const float4* __restrict__ part,
                                                     float* __restrict__ out) {
  __shared__ double wsum[4][4];
  const int tid = threadIdx.x;
  const int lane = tid & 63, wid = tid >> 6;
  double s0 = 0.0, s1 = 0.0, s2 = 0.0, s3 = 0.0;
  for (int k = tid; k < NROW; k += 256) {
    float4 v = part[k];
    s0 += (double)v.x; s1 += (double)v.y; s2 += (double)v.z; s3 += (double)v.w;
  }
  for (int o = 32; o > 0; o >>= 1) {
    s0 += __shfl_down(s0, o); s1 += __shfl_down(s1, o);
    s2 += __shfl_down(s2, o); s3 += __shfl_down(s3, o);
  }
  if (lane == 0) {
    wsum[wid][0] = s0; wsum[wid][1] = s1; wsum[wid][2] = s2; wsum[wid][3] = s3;
  }
  __syncthreads();
  if (tid == 0) {
    double a0 = wsum[0][0] + wsum[1][0] + wsum[2][0] + wsum[3][0];
    double a1 = wsum[0][1] + wsum[1][1] + wsum[2][1] + wsum[3][1];
    double a2 = wsum[0][2] + wsum[1][2] + wsum[2][2] + wsum[3][2];
    double a3 = wsum[0][3] + wsum[1][3] + wsum[2][3] + wsum[3][3];
    out[0] = (float)(a0 / (double)NROW);
    out[1] = (float)(1.0 - a1 / (double)NROW);
    out[2] = (float)(a2 / ((double)NROW * 3.0));
    out[3] = (float)(a3 / ((double)NROW * (double)KNEG));
  }
}

extern "C" void kernel_launch(void* const* d_in, const int* in_sizes, int n_in,
                              void* d_out, int out_size, void* d_ws, size_t ws_size,
                              hipStream_t stream) {
  (void)in_sizes; (void)n_in; (void)out_size;
  const float* X = (const float*)d_in[0];
  float* out = (float*)d_out;
  char* ws = (char*)d_ws;

  ushort* distb = (ushort*)ws;                                     // 32 MiB bf16
  size_t off = (size_t)NROW * NROW * sizeof(ushort);
  float* sq = (float*)(ws + off);            off += NROW * sizeof(float);
  ushort* Xbf = (ushort*)(ws + off);         off += (size_t)NROW * NDIM * sizeof(ushort);
  float4* part = (float4*)(ws + off);        off += (size_t)NROW * sizeof(float4);
  // fp16 Gumbel table (32 MB) — only if workspace allows; else inline fallback
  ushort* Gh = nullptr;
  if (ws_size >= off + GTOT * sizeof(ushort)) Gh = (ushort*)(ws + off);

  prep_kernel<<<NROW / 4, 256, 0, stream>>>(X, sq, Xbf);
  dist_gumbel<<<DISTBLKS, 256, 0, stream>>>(Xbf, sq, distb, Gh);
  row_kernel<<<NROW, 256, 0, stream>>>(distb, Gh, part);
  reduce_kernel<<<1, 256, 0, stream>>>(part, out);
}

// Round 4
// 150.509 us; speedup vs baseline: 1.9975x; 1.0308x over previous
//
#include <hip/hip_runtime.h>
#include <stdint.h>

#define NROW 4096
#define NDIM 128
#define KNEG 4092
#define INF_VAL 1e30f
#define BUCKETS 2048
#define DISTBLKS 1024                         // 32x32 tiles of 128x128
#define DSTR 68

typedef __attribute__((ext_vector_type(8))) short short8;
typedef __attribute__((ext_vector_type(4))) float f32x4;

// ---------------- Threefry-2x32-20, key = (0, 42) ----------------
__device__ __forceinline__ uint32_t rotl32(uint32_t v, int d) {
  return __builtin_rotateleft32(v, (unsigned)d);
}

__device__ __forceinline__ void threefry2x32(uint32_t x0, uint32_t x1,
                                             uint32_t& y0, uint32_t& y1) {
  const uint32_t k0 = 0u, k1 = 42u;
  const uint32_t k2 = 0x1BD11BDAu ^ k0 ^ k1;
  uint32_t v0 = x0 + k0, v1 = x1 + k1;
#define TF_R(r) v0 += v1; v1 = rotl32(v1, r); v1 ^= v0;
  TF_R(13) TF_R(15) TF_R(26) TF_R(6)
  v0 += k1; v1 += k2 + 1u;
  TF_R(17) TF_R(29) TF_R(16) TF_R(24)
  v0 += k2; v1 += k0 + 2u;
  TF_R(13) TF_R(15) TF_R(26) TF_R(6)
  v0 += k0; v1 += k1 + 3u;
  TF_R(17) TF_R(29) TF_R(16) TF_R(24)
  v0 += k1; v1 += k2 + 4u;
  TF_R(13) TF_R(15) TF_R(26) TF_R(6)
  v0 += k2; v1 += k0 + 5u;
#undef TF_R
  y0 = v0; y1 = v1;
}

__device__ __forceinline__ float gumbel_ref(uint32_t f) {
  uint32_t y0, y1;
  threefry2x32(0u, f, y0, y1);
  uint32_t m = y1 >> 9;
  float fm = (float)m;                                     // exact (m < 2^24)
  float nl = fmaf(-0.69314718f, __log2f(fm), 15.942385f);  // ln2*(23-log2 m)
  if (m == 0u) nl = 87.33655f;                             // -log(tiny)
  return -0.69314718f * __log2f(nl);
}

__device__ __forceinline__ float softplus_ref(float x) {
  return fmaxf(x, 0.0f) + log1pf(expf(-fabsf(x)));
}

__device__ __forceinline__ ushort f2h(float f) {
  _Float16 h = (_Float16)f;
  return *(ushort*)&h;
}
__device__ __forceinline__ float h2f(ushort u) {
  _Float16 h = *(_Float16*)&u;
  return (float)h;
}
__device__ __forceinline__ float bf2f(ushort u) {
  return __uint_as_float(((uint32_t)u) << 16);
}
__device__ __forceinline__ ushort f2bf(float f) {
  uint32_t u = __float_as_uint(f);
  u += 0x7fffu + ((u >> 16) & 1u);
  return (ushort)(u >> 16);
}

// fp16-roundtripped gumbel — BIT-IDENTICAL to the old table path
// (table stored f2h(gumbel_ref(idx)); reader did h2f of that).
__device__ __forceinline__ ushort gumbel_h(uint32_t f) {
  return f2h(gumbel_ref(f));
}

// bucket = bf16 code (monotone & injective for positive floats); every bucket
// holds only exactly-equal values => scatter position IS the exact rank.
__device__ __forceinline__ int bucket_code(ushort code) {
  return min(max((int)code - 0x4000, 0), BUCKETS - 1);
}

// monotone u32 key for f32 (total order, matches > on non-NaN floats)
__device__ __forceinline__ uint32_t fkey(float f) {
  uint32_t b = __float_as_uint(f);
  return b ^ ((uint32_t)((int32_t)b >> 31) | 0x80000000u);
}

// branchless insert into sorted-descending u64 triple
__device__ __forceinline__ void ins3(uint64_t v, uint64_t& t0, uint64_t& t1,
                                     uint64_t& t2) {
  bool c0 = v > t0, c1 = v > t1, c2 = v > t2;
  t2 = c1 ? t1 : (c2 ? v : t2);
  t1 = c0 ? t0 : (c1 ? v : t1);
  t0 = c0 ? v : t0;
}

// merge two sorted-descending triples -> top-3 in (a0,a1,a2)
__device__ __forceinline__ void merge3(uint64_t& a0, uint64_t& a1, uint64_t& a2,
                                       uint64_t b0, uint64_t b1, uint64_t b2) {
  bool sw = b0 > a0;
  uint64_t n0 = sw ? b0 : a0, m0 = sw ? a0 : b0;
  uint64_t n1 = sw ? b1 : a1, m1 = sw ? a1 : b1;
  uint64_t n2 = sw ? b2 : a2;
  a0 = n0;
  bool c = n1 >= m0;  // distinct keys, >= == >
  a1 = c ? n1 : m0;
  uint64_t u = c ? n2 : n1;
  uint64_t w = c ? m0 : m1;
  a2 = (u > w) ? u : w;
}

// ---------------- kernel A: sumsq + fp32->bf16 convert (4 rows/block) -------
__global__ __launch_bounds__(256) void prep_kernel(const float* __restrict__ X,
                                                   float* __restrict__ sq,
                                                   ushort* __restrict__ Xbf) {
  const int tid = threadIdx.x;
  const int lane = tid & 63;
  const int i = (blockIdx.x << 2) + (tid >> 6);
  float2 v = ((const float2*)(X + (size_t)i * NDIM))[lane];
  float s = v.x * v.x + v.y * v.y;
  for (int o = 32; o > 0; o >>= 1) s += __shfl_down(s, o);
  if (lane == 0) sq[i] = s;
  ushort2 h;
  h.x = f2bf(v.x);
  h.y = f2bf(v.y);
  ((ushort2*)(Xbf + (size_t)i * NDIM))[lane] = h;
}

// ---------------- kernel B: dist tile per block (no gumbel anymore) ---------
__global__ __launch_bounds__(256) void dist_kernel(const ushort* __restrict__ Xbf,
                                                   const float* __restrict__ sq,
                                                   ushort* __restrict__ distb) {
  __shared__ ushort Als[128 * DSTR];
  __shared__ ushort Bls[128 * DSTR];
  const int tid = threadIdx.x;
  const int bi = blockIdx.x >> 5, bj = blockIdx.x & 31;
  const int wave = tid >> 6, lane = tid & 63;
  const int q = lane >> 4, ln = lane & 15;
  const ushort* Ag = Xbf + (size_t)bi * 128 * NDIM;
  const ushort* Bg = Xbf + (size_t)bj * 128 * NDIM;

  f32x4 acc[8][2];
#pragma unroll
  for (int mt = 0; mt < 8; ++mt)
#pragma unroll
    for (int nt = 0; nt < 2; ++nt) acc[mt][nt] = (f32x4){0.f, 0.f, 0.f, 0.f};

  for (int kh = 0; kh < 2; ++kh) {
    if (kh) __syncthreads();
#pragma unroll
    for (int t = 0; t < 4; ++t) {
      int c = tid + 256 * t;
      int r = c >> 3, k8 = (c & 7) << 3;
      *(short8*)&Als[r * DSTR + k8] =
          *(const short8*)(Ag + (size_t)r * NDIM + kh * 64 + k8);
      *(short8*)&Bls[r * DSTR + k8] =
          *(const short8*)(Bg + (size_t)r * NDIM + kh * 64 + k8);
    }
    __syncthreads();
#pragma unroll
    for (int k0 = 0; k0 < 64; k0 += 32) {
      int kf = k0 + q * 8;
      short8 a[8], b[2];
#pragma unroll
      for (int mt = 0; mt < 8; ++mt)
        a[mt] = *(const short8*)&Als[(mt * 16 + ln) * DSTR + kf];
      // lane owns ADJACENT cols 2*ln, 2*ln+1 -> packed bf16x2 dword stores
#pragma unroll
      for (int nt = 0; nt < 2; ++nt)
        b[nt] = *(const short8*)&Bls[(wave * 32 + 2 * ln + nt) * DSTR + kf];
#pragma unroll
      for (int mt = 0; mt < 8; ++mt)
#pragma unroll
        for (int nt = 0; nt < 2; ++nt)
          acc[mt][nt] = __builtin_amdgcn_mfma_f32_16x16x32_bf16(
              a[mt], b[nt], acc[mt][nt], 0, 0, 0);
    }
  }

  const int jcol = bj * 128 + wave * 32 + 2 * ln;
  float sqj0 = sq[jcol], sqj1 = sq[jcol + 1];
#pragma unroll
  for (int mt = 0; mt < 8; ++mt) {
    int ibase = bi * 128 + mt * 16 + q * 4;
#pragma unroll
    for (int r = 0; r < 4; ++r) {
      int i = ibase + r;
      float sqi = sq[i];
      float dx = sqrtf(fmaxf(sqi + sqj0 - 2.0f * acc[mt][0][r], 1e-12f));
      float dy = sqrtf(fmaxf(sqi + sqj1 - 2.0f * acc[mt][1][r], 1e-12f));
      uint32_t pack = ((uint32_t)f2bf(dy) << 16) | (uint32_t)f2bf(dx);
      *(uint32_t*)(distb + (size_t)i * NROW + jcol) = pack;
    }
  }
}

// ---------------- kernel C: per-row rank + sample + loss --------------------
// Gumbel computed INLINE (indices are static per thread: fbase + tid + 256*qq),
// fp16-roundtripped => bit-identical to the old precomputed table. Computed
// early so the ~1.1K independent VALU ops fill load-latency and shuffle-chain
// bubbles of the histogram/prefix phases.
__global__ __launch_bounds__(256) void row_kernel(const ushort* __restrict__ distb,
                                                  float4* __restrict__ part) {
  __shared__ alignas(16) ushort sortc[NROW];   // 8 KB (bf16 codes, rank-ordered)
  __shared__ alignas(16) int base[BUCKETS];    // 8 KB (bucket STARTs)
  __shared__ float wredf[8];
  __shared__ int wtot[4];
  __shared__ float s_pos[3];
  __shared__ int s_selp[3];

  // alias — live only after the score pass (base is dead after scatter)
  uint64_t* cand = (uint64_t*)base;            // 768 * 8B = 6 KB

  const int i = blockIdx.x;
  const int tid = threadIdx.x;
  const int lane = tid & 63, wid = tid >> 6;
  const ushort* row = distb + (size_t)i * NROW;
  const int gbase = i & ~3;
  const uint32_t fbase = (uint32_t)i * (uint32_t)KNEG;

  {
    int4* b4 = (int4*)base;
    b4[tid] = (int4){0, 0, 0, 0};
    b4[tid + 256] = (int4){0, 0, 0, 0};
  }

  // issue row loads first; gumbel fills the latency
  short8 r0 = *(const short8*)(row + tid * 16);
  short8 r1 = *(const short8*)(row + tid * 16 + 8);

  // 16 gumbels, packed fp16 pairs (8 VGPRs). qq=2j -> lo, qq=2j+1 -> hi.
  uint32_t gpack[8];
#pragma unroll
  for (int j = 0; j < 8; ++j) {
    uint32_t lo = (uint32_t)gumbel_h(fbase + (uint32_t)(tid + 512 * j));
    uint32_t hi = (uint32_t)gumbel_h(fbase + (uint32_t)(tid + 512 * j + 256));
    gpack[j] = lo | (hi << 16);
  }

  ushort cd[16];
  float x[16];
#pragma unroll
  for (int k = 0; k < 8; ++k) {
    cd[k] = (ushort)r0[k];     x[k] = bf2f(cd[k]);
    cd[8 + k] = (ushort)r1[k]; x[8 + k] = bf2f(cd[8 + k]);
  }

  if (tid == (gbase >> 4)) {
    float p[3]; int np = 0;
#pragma unroll
    for (int qq = 0; qq < 4; ++qq) {
      int j = gbase + qq;
      if (j != i) p[np++] = x[j & 15];
    }
    float a = p[0], b = p[1], c = p[2], t_;
    if (a > b) { t_ = a; a = b; b = t_; }
    if (b > c) { t_ = b; b = c; c = t_; }
    if (a > b) { t_ = a; a = b; b = t_; }
    s_pos[0] = a; s_pos[1] = b; s_pos[2] = c;
  }

#pragma unroll
  for (int qq = 0; qq < 16; ++qq) {
    int j = tid * 16 + qq;
    if ((j >> 2) == (i >> 2)) { x[qq] = INF_VAL; cd[qq] = 0x7F80u; }
  }
  __syncthreads();

  int bkt[16];
  int ord[16];
  float ls = 0.f;
#pragma unroll
  for (int qq = 0; qq < 16; ++qq) {
    bkt[qq] = bucket_code(cd[qq]);
    ord[qq] = atomicAdd(&base[bkt[qq]], 1);
    if (x[qq] < 1e29f) ls += x[qq];
  }
  for (int o = 32; o > 0; o >>= 1) ls += __shfl_down(ls, o);
  if (lane == 0) wredf[wid] = ls;
  __syncthreads();
  const float negsum = wredf[0] + wredf[1] + wredf[2] + wredf[3];
  const float mean = negsum / (float)KNEG;

  int c8[8]; int lsum = 0;
#pragma unroll
  for (int qq = 0; qq < 8; ++qq) {
    int t_ = base[tid * 8 + qq];
    c8[qq] = lsum; lsum += t_;
  }
  float ls2 = 0.f;
#pragma unroll
  for (int qq = 0; qq < 16; ++qq)
    if (x[qq] < 1e29f) { float z = x[qq] - mean; ls2 += z * z; }
  int incl = lsum;
  for (int off = 1; off < 64; off <<= 1) {
    int o = __shfl_up(incl, off);
    if (lane >= off) incl += o;
  }
  for (int o = 32; o > 0; o >>= 1) ls2 += __shfl_down(ls2, o);
  if (lane == 63) wtot[wid] = incl;
  if (lane == 0) wredf[4 + wid] = ls2;
  __syncthreads();
  const float var = (wredf[4] + wredf[5] + wredf[6] + wredf[7]) / (float)KNEG;
  const float stdv = sqrtf(var);
  const float rdenom = __frcp_rn(2.0f * stdv * stdv);
  int excl = incl - lsum;
#pragma unroll
  for (int w = 0; w < 4; ++w) if (w < wid) excl += wtot[w];
#pragma unroll
  for (int qq = 0; qq < 8; ++qq) base[tid * 8 + qq] = excl + c8[qq];
  __syncthreads();

  // ---- place CODES: pos = start + ordinal (EXACT rank) ----
#pragma unroll
  for (int qq = 0; qq < 16; ++qq) {
    int p = base[bkt[qq]] + ord[qq];
    sortc[p] = cd[qq];
  }
  __syncthreads();  // last read of base (scatter) done; cand alias free

  // ---- score/top-3: packed u64, branchless insert ----
  uint64_t t0 = 0, t1 = 0, t2 = 0;  // 0 < key of any real float
#pragma unroll
  for (int qq = 0; qq < 16; ++qq) {
    int p = tid + 256 * qq;
    float xv = bf2f(sortc[p]);
    if (p < KNEG) {
      float z = xv - mean;
      uint32_t gp = gpack[qq >> 1];
      ushort gc = (qq & 1) ? (ushort)(gp >> 16) : (ushort)(gp & 0xffffu);
      float gv = h2f(gc);
      float sv = fmaf(z * z, rdenom, gv);
      uint64_t v = ((uint64_t)fkey(sv) << 32) | (uint32_t)(8192 - p);
      ins3(v, t0, t1, t2);
    }
  }
  // sortc stays intact (read again at the end); cand only aliases base
  cand[tid * 3 + 0] = t0;
  cand[tid * 3 + 1] = t1;
  cand[tid * 3 + 2] = t2;
  __syncthreads();

  // ---- single-pass block top-3: wave 0 scans 768 + shfl_xor triple-merge ---
  if (wid == 0) {
    uint64_t a0 = 0, a1 = 0, a2 = 0;
#pragma unroll
    for (int k = 0; k < 12; ++k) {
      uint64_t v = cand[lane + 64 * k];
      ins3(v, a0, a1, a2);
    }
#pragma unroll
    for (int m = 32; m > 0; m >>= 1) {
      uint64_t b0 = __shfl_xor((unsigned long long)a0, m);
      uint64_t b1 = __shfl_xor((unsigned long long)a1, m);
      uint64_t b2 = __shfl_xor((unsigned long long)a2, m);
      merge3(a0, a1, a2, b0, b1, b2);
    }
    if (lane == 0) {
      s_selp[0] = 8192 - (int)(uint32_t)a0;
      s_selp[1] = 8192 - (int)(uint32_t)a1;
      s_selp[2] = 8192 - (int)(uint32_t)a2;
    }
  }
  __syncthreads();

  if (tid == 0) {
    float p0 = s_pos[0], p1 = s_pos[1], p2 = s_pos[2];
    float thr = p2 + 0.05f;
    float samp[3]; bool kept[3]; int cnt = 0;
#pragma unroll
    for (int t = 0; t < 3; ++t) {
      samp[t] = bf2f(sortc[s_selp[t]]);
      kept[t] = samp[t] < thr;
      cnt += kept[t] ? 1 : 0;
    }
    bool any = cnt > 0;
    float pos_loss = 0.5f *
        (softplus_ref(-2.0f * (1.0f - p0)) + softplus_ref(-2.0f * (1.0f - p1)) +
         softplus_ref(-2.0f * (1.0f - p2))) / 3.0f;
    float nsum = 0.0f;
#pragma unroll
    for (int t = 0; t < 3; ++t)
      if (kept[t]) nsum += softplus_ref(20.0f * (1.0f - samp[t]));
    float neg_loss = 0.05f * nsum / (float)(cnt > 0 ? cnt : 1);
    float row_loss = any ? (pos_loss + neg_loss) : 0.0f;
    int first = kept[0] ? 0 : (kept[1] ? 1 : (kept[2] ? 2 : 0));
    float neg0 = samp[first];
    float errv = (any && (p0 < neg0 - 0.1f)) ? 1.0f : 0.0f;
    float4 pr;
    pr.x = row_loss; pr.y = errv; pr.z = p0 + p1 + p2; pr.w = negsum;
    part[i] = pr;
  }
}

// ---------------- reduce: 4096 float4 partials -> 4 outputs ----------------
__global__ __launch_bounds__(256) void reduce_kernel(const float4* __restrict__ part,
                                                     float* __restrict__ out) {
  __shared__ double wsum[4][4];
  const int tid = threadIdx.x;
  const int lane = tid & 63, wid = tid >> 6;
  double s0 = 0.0, s1 = 0.0, s2 = 0.0, s3 = 0.0;
  for (int k = tid; k < NROW; k += 256) {
    float4 v = part[k];
    s0 += (double)v.x; s1 += (double)v.y; s2 += (double)v.z; s3 += (double)v.w;
  }
  for (int o = 32; o > 0; o >>= 1) {
    s0 += __shfl_down(s0, o); s1 += __shfl_down(s1, o);
    s2 += __shfl_down(s2, o); s3 += __shfl_down(s3, o);
  }
  if (lane == 0) {
    wsum[wid][0] = s0; wsum[wid][1] = s1; wsum[wid][2] = s2; wsum[wid][3] = s3;
  }
  __syncthreads();
  if (tid == 0) {
    double a0 = wsum[0][0] + wsum[1][0] + wsum[2][0] + wsum[3][0];
    double a1 = wsum[0][1] + wsum[1][1] + wsum[2][1] + wsum[3][1];
    double a2 = wsum[0][2] + wsum[1][2] + wsum[2][2] + wsum[3][2];
    double a3 = wsum[0][3] + wsum[1][3] + wsum[2][3] + wsum[3][3];
    out[0] = (float)(a0 / (double)NROW);
    out[1] = (float)(1.0 - a1 / (double)NROW);
    out[2] = (float)(a2 / ((double)NROW * 3.0));
    out[3] = (float)(a3 / ((double)NROW * (double)KNEG));
  }
}

extern "C" void kernel_launch(void* const* d_in, const int* in_sizes, int n_in,
                              void* d_out, int out_size, void* d_ws, size_t ws_size,
                              hipStream_t stream) {
  (void)in_sizes; (void)n_in; (void)out_size; (void)ws_size;
  const float* X = (const float*)d_in[0];
  float* out = (float*)d_out;
  char* ws = (char*)d_ws;

  ushort* distb = (ushort*)ws;                                     // 32 MiB bf16
  size_t off = (size_t)NROW * NROW * sizeof(ushort);
  float* sq = (float*)(ws + off);            off += NROW * sizeof(float);
  ushort* Xbf = (ushort*)(ws + off);         off += (size_t)NROW * NDIM * sizeof(ushort);
  float4* part = (float4*)(ws + off);        off += (size_t)NROW * sizeof(float4);

  prep_kernel<<<NROW / 4, 256, 0, stream>>>(X, sq, Xbf);
  dist_kernel<<<DISTBLKS, 256, 0, stream>>>(Xbf, sq, distb);
  row_kernel<<<NROW, 256, 0, stream>>>(distb, part);
  reduce_kernel<<<1, 256, 0, stream>>>(part, out);
}